// Round 17
// baseline (95.251 us; speedup 1.0000x reference)
//
#include <hip/hip_runtime.h>

#define CD_B 4
#define CD_N 4096
#define CD_TOTAL (CD_B * CD_N)   // 16384 points per array
#define TILE 256

typedef float v2f __attribute__((ext_vector_type(2)));

// ---------------- Kernel A: tiled partial mins (the heavy kernel) ----------
// Grid: 2 dirs x 4 batches x 16 own-tiles x 16 stream-tiles = 2048 blocks,
// 256 threads -> 8 blocks/CU = 8 waves/SIMD (two independent blocks per SIMD
// cover each other's LDS-latency and barrier stalls; the 4-waves/SIMD version
// was latency-bound, not issue-bound).
// Each block: stage own-tile + stream-tile in SoA LDS (x/y/z/norm), compute
// ONE direction. dist via |p-g|^2 = |p|^2 + (|g|^2 - 2 p.g); inner loop in
// float2 ext-vectors (v_pk_fma_f32 / v_pk_min_f32). Lane owns 4 points, the
// 4 waves split the streamed 256 into 64 each; partials combine via LDS;
// plain coalesced stores to pm (no atomics).
// pm layout: [dir][b][own_tile][stream_tile][256]
__global__ __launch_bounds__(256, 8) void cd_tiles(const float* __restrict__ recon,
                                                   const float* __restrict__ gt,
                                                   float* __restrict__ pm,
                                                   float* __restrict__ out) {
    const int bid = blockIdx.x;
    const int dir = bid >> 10;         // 0: recon->gt, 1: gt->recon
    const int rem = bid & 1023;
    const int b   = rem >> 8;
    const int ti  = (rem >> 4) & 15;   // own tile index
    const int tj  = rem & 15;          // stream tile index
    const int t   = threadIdx.x;
    const int w   = t >> 6;   // wave 0..3
    const int l   = t & 63;   // lane

    if (bid == 0 && t == 0) out[0] = 0.f;   // kernel B accumulates after us

    const float* op = dir ? gt : recon;     // own set
    const float* sp = dir ? recon : gt;     // streamed set

    __shared__ alignas(16) float oxs[TILE], oys[TILE], ozs[TILE], ons[TILE];
    __shared__ alignas(16) float sxs[TILE], sys[TILE], szs[TILE], sns[TILE];
    __shared__ float part[4][TILE];

    {   // Stage: thread t loads point t of each tile, computes norms (SoA).
        const float* o = op + ((size_t)(b * CD_N + ti * TILE) + t) * 3;
        const float* s = sp + ((size_t)(b * CD_N + tj * TILE) + t) * 3;
        const float ox = o[0], oy = o[1], oz = o[2];
        const float sx = s[0], sy = s[1], sz = s[2];
        oxs[t] = ox; oys[t] = oy; ozs[t] = oz;
        ons[t] = fmaf(oz, oz, fmaf(oy, oy, ox * ox));
        sxs[t] = sx; sys[t] = sy; szs[t] = sz;
        sns[t] = fmaf(sz, sz, fmaf(sy, sy, sx * sx));
    }
    __syncthreads();

    const float INF = __builtin_inff();

    // Lane l owns points {l, 64+l, 128+l, 192+l}; wave w streams [64w, 64w+64).
    {
        const v2f a0x = -2.f * oxs[l],       a0y = -2.f * oys[l],       a0z = -2.f * ozs[l];
        const v2f a1x = -2.f * oxs[64 + l],  a1y = -2.f * oys[64 + l],  a1z = -2.f * ozs[64 + l];
        const v2f a2x = -2.f * oxs[128 + l], a2y = -2.f * oys[128 + l], a2z = -2.f * ozs[128 + l];
        const v2f a3x = -2.f * oxs[192 + l], a3y = -2.f * oys[192 + l], a3z = -2.f * ozs[192 + l];
        v2f m0 = INF, m1 = INF, m2 = INF, m3 = INF;
        const int jbase = w << 6;
        #pragma unroll 8
        for (int jj = 0; jj < 64; jj += 2) {
            const int j = jbase + jj;
            const v2f sx = *(const v2f*)&sxs[j];   // broadcast ds_read_b64
            const v2f sy = *(const v2f*)&sys[j];
            const v2f sz = *(const v2f*)&szs[j];
            const v2f sn = *(const v2f*)&sns[j];
            v2f d;
            d = __builtin_elementwise_fma(a0z, sz, sn);
            d = __builtin_elementwise_fma(a0y, sy, d);
            d = __builtin_elementwise_fma(a0x, sx, d);
            m0 = __builtin_elementwise_min(m0, d);
            d = __builtin_elementwise_fma(a1z, sz, sn);
            d = __builtin_elementwise_fma(a1y, sy, d);
            d = __builtin_elementwise_fma(a1x, sx, d);
            m1 = __builtin_elementwise_min(m1, d);
            d = __builtin_elementwise_fma(a2z, sz, sn);
            d = __builtin_elementwise_fma(a2y, sy, d);
            d = __builtin_elementwise_fma(a2x, sx, d);
            m2 = __builtin_elementwise_min(m2, d);
            d = __builtin_elementwise_fma(a3z, sz, sn);
            d = __builtin_elementwise_fma(a3y, sy, d);
            d = __builtin_elementwise_fma(a3x, sx, d);
            m3 = __builtin_elementwise_min(m3, d);
        }
        part[w][l]       = fminf(m0[0], m0[1]);
        part[w][64 + l]  = fminf(m1[0], m1[1]);
        part[w][128 + l] = fminf(m2[0], m2[1]);
        part[w][192 + l] = fminf(m3[0], m3[1]);
    }
    __syncthreads();
    {   // combine wave partials for own point t; add |p|^2; plain store
        const float v = fminf(fminf(part[0][t], part[1][t]),
                              fminf(part[2][t], part[3][t]));
        const float dist = fmaxf(v + ons[t], 0.f);
        pm[(dir << 18) + (((b << 4) + ti) << 12) + (tj << 8) + t] = dist;
    }
}

// ---------------- Kernel B: gather 16 partials per point, sum, accumulate ---
// 128 blocks x 256 threads = 32768 threads, one per (dir, b, own_tile, p).
__global__ __launch_bounds__(256) void cd_gather(const float* __restrict__ pm,
                                                 float* __restrict__ out) {
    const int tid = blockIdx.x * 256 + threadIdx.x;  // [0, 32768)
    const int p   = tid & 255;
    const int ot  = (tid >> 8) & 15;
    const int gb  = tid >> 12;                       // dir*4 + b, [0,8)
    const float* base = pm + ((((gb << 4) + ot) << 4) << 8) + p;

    float m = base[0];
    #pragma unroll
    for (int st = 1; st < 16; ++st) m = fminf(m, base[st << 8]);

    for (int off = 32; off; off >>= 1) m += __shfl_down(m, off);
    __shared__ float ws[4];
    const int t = threadIdx.x;
    if ((t & 63) == 0) ws[t >> 6] = m;
    __syncthreads();
    if (t == 0) {
        const float s = ws[0] + ws[1] + ws[2] + ws[3];
        atomicAdd(out, s * (0.5f / (float)CD_TOTAL));  // (mean1+mean2)/2
    }
}

extern "C" void kernel_launch(void* const* d_in, const int* in_sizes, int n_in,
                              void* d_out, int out_size, void* d_ws, size_t ws_size,
                              hipStream_t stream) {
    const float* recon = (const float*)d_in[0];
    const float* gt    = (const float*)d_in[1];
    float* pm  = (float*)d_ws;     // 2*4*16*16*256 floats = 2 MB
    float* out = (float*)d_out;

    cd_tiles<<<2 * CD_B * 16 * 16, 256, 0, stream>>>(recon, gt, pm, out);
    cd_gather<<<128, 256, 0, stream>>>(pm, out);
}

// Round 18
// 68.464 us; speedup vs baseline: 1.3913x; 1.3913x over previous
//
#include <hip/hip_runtime.h>

#define CD_B 4
#define CD_N 4096
#define CD_TOTAL (CD_B * CD_N)   // 16384 points per array
#define TILE_O 512               // owned points per block (8 per lane)
#define TILE_S 256               // streamed points per block

typedef float v2f __attribute__((ext_vector_type(2)));

// ---------------- Kernel A: tiled partial mins (the heavy kernel) ----------
// Grid: 2 dirs x 4 batches x 8 own-tiles(512) x 16 stream-tiles(256) = 1024
// blocks, 256 threads (4 waves). R=8 register blocking: lane l owns the 8
// points {64k+l}; wave w streams the quarter [64w, 64w+64) of the 256
// streamed points. Per 2-streamed-point step: 4 ds_read_b64 (broadcast) then
// 40 packed VALU ops (~80 cyc) -> LDS latency fully covered by VALU work
// (the R=4 version had only ~32 cyc between reads and measured ~3.5x its
// issue floor). dist via |p-g|^2 = |p|^2 + (|g|^2 - 2 p.g).
// Wave partials combine via LDS; plain coalesced stores to pm (no atomics).
// pm layout: [dir][b][ot(8)][st(16)][512]
__global__ __launch_bounds__(256, 4) void cd_tiles(const float* __restrict__ recon,
                                                   const float* __restrict__ gt,
                                                   float* __restrict__ pm,
                                                   float* __restrict__ out) {
    const int bid = blockIdx.x;
    const int dir = bid >> 9;          // 0: recon->gt, 1: gt->recon
    const int rem = bid & 511;
    const int b   = rem >> 7;          // batch
    const int ot  = (rem >> 4) & 7;    // own tile (512 points)
    const int st  = rem & 15;          // stream tile (256 points)
    const int t   = threadIdx.x;
    const int w   = t >> 6;   // wave 0..3
    const int l   = t & 63;   // lane

    if (bid == 0 && t == 0) out[0] = 0.f;   // kernel B accumulates after us

    const float* op = dir ? gt : recon;     // own set
    const float* sp = dir ? recon : gt;     // streamed set

    __shared__ alignas(16) float oxs[TILE_O], oys[TILE_O], ozs[TILE_O], ons[TILE_O];
    __shared__ alignas(16) float sxs[TILE_S], sys[TILE_S], szs[TILE_S], sns[TILE_S];
    __shared__ float part[4][TILE_O];       // per-wave partial mins

    {   // Stage (SoA + norms): thread t loads own points {t, 256+t}, stream point t.
        const size_t ob = (size_t)(b * CD_N + ot * TILE_O);
        const float* o0 = op + (ob + t) * 3;
        const float* o1 = op + (ob + 256 + t) * 3;
        const float* s  = sp + ((size_t)(b * CD_N + st * TILE_S) + t) * 3;
        float x, y, z;
        x = o0[0]; y = o0[1]; z = o0[2];
        oxs[t] = x; oys[t] = y; ozs[t] = z;
        ons[t] = fmaf(z, z, fmaf(y, y, x * x));
        x = o1[0]; y = o1[1]; z = o1[2];
        oxs[256 + t] = x; oys[256 + t] = y; ozs[256 + t] = z;
        ons[256 + t] = fmaf(z, z, fmaf(y, y, x * x));
        x = s[0]; y = s[1]; z = s[2];
        sxs[t] = x; sys[t] = y; szs[t] = z;
        sns[t] = fmaf(z, z, fmaf(y, y, x * x));
    }
    __syncthreads();

    const float INF = __builtin_inff();

    {   // Main: lane l owns points {64k+l, k=0..7}; wave w streams [64w,64w+64).
        v2f ax[8], ay[8], az[8], acc[8];
        #pragma unroll
        for (int k = 0; k < 8; ++k) {
            const int p = (k << 6) + l;
            ax[k] = -2.f * oxs[p];
            ay[k] = -2.f * oys[p];
            az[k] = -2.f * ozs[p];
            acc[k] = INF;
        }
        const int jbase = w << 6;
        #pragma unroll 4
        for (int jj = 0; jj < 64; jj += 2) {
            const int j = jbase + jj;
            const v2f sx = *(const v2f*)&sxs[j];   // broadcast ds_read_b64
            const v2f sy = *(const v2f*)&sys[j];
            const v2f sz = *(const v2f*)&szs[j];
            const v2f sn = *(const v2f*)&sns[j];
            #pragma unroll
            for (int k = 0; k < 8; ++k) {
                v2f d;
                d = __builtin_elementwise_fma(az[k], sz, sn);
                d = __builtin_elementwise_fma(ay[k], sy, d);
                d = __builtin_elementwise_fma(ax[k], sx, d);
                acc[k] = __builtin_elementwise_min(acc[k], d);
            }
        }
        #pragma unroll
        for (int k = 0; k < 8; ++k)
            part[w][(k << 6) + l] = fminf(acc[k][0], acc[k][1]);
    }
    __syncthreads();

    {   // Epilogue: thread t finalizes own points {t, 256+t}: 4-way wave
        // combine, add |p|^2, clamp, coalesced store.
        #pragma unroll
        for (int h = 0; h < 2; ++h) {
            const int p = (h << 8) + t;
            const float v = fminf(fminf(part[0][p], part[1][p]),
                                  fminf(part[2][p], part[3][p]));
            const float dist = fmaxf(v + ons[p], 0.f);
            pm[((((((dir << 2) + b) << 3) + ot) << 4) + st) * TILE_O + p] = dist;
        }
    }
}

// ---------------- Kernel B: gather 16 partials per point, sum, accumulate ---
// 128 blocks x 256 threads = 32768 threads, one per (dir, b, ot, p).
// 16 coalesced loads at stride 512 floats, 15 mins, block sum, one atomicAdd.
__global__ __launch_bounds__(256) void cd_gather(const float* __restrict__ pm,
                                                 float* __restrict__ out) {
    const int tid = blockIdx.x * 256 + threadIdx.x;  // [0, 32768)
    const int p   = tid & 511;
    const int ot  = (tid >> 9) & 7;
    const int gb  = tid >> 12;                       // dir*4 + b, [0,8)
    const float* base = pm + (size_t)(((gb << 3) + ot) << 4) * TILE_O + p;

    float m = base[0];
    #pragma unroll
    for (int s = 1; s < 16; ++s) m = fminf(m, base[s << 9]);

    for (int off = 32; off; off >>= 1) m += __shfl_down(m, off);
    __shared__ float ws[4];
    const int t = threadIdx.x;
    if ((t & 63) == 0) ws[t >> 6] = m;
    __syncthreads();
    if (t == 0) {
        const float s = ws[0] + ws[1] + ws[2] + ws[3];
        atomicAdd(out, s * (0.5f / (float)CD_TOTAL));  // (mean1+mean2)/2
    }
}

extern "C" void kernel_launch(void* const* d_in, const int* in_sizes, int n_in,
                              void* d_out, int out_size, void* d_ws, size_t ws_size,
                              hipStream_t stream) {
    const float* recon = (const float*)d_in[0];
    const float* gt    = (const float*)d_in[1];
    float* pm  = (float*)d_ws;     // 2*4*8*16*512 floats = 2 MB
    float* out = (float*)d_out;

    cd_tiles<<<1024, 256, 0, stream>>>(recon, gt, pm, out);
    cd_gather<<<128, 256, 0, stream>>>(pm, out);
}